// Round 1
// baseline (625.918 us; speedup 1.0000x reference)
//
#include <hip/hip_runtime.h>
#include <hip/hip_bf16.h>

#define N_IN 512
#define HID 32
#define OUTD 40
#define NWIN 8  // fill windows: csr region per window ~800 KB -> L2-resident writes

typedef __attribute__((ext_vector_type(8))) short bf16x8;
typedef __attribute__((ext_vector_type(4))) float f32x4;

// ---------------- degree / CSR build ----------------

__global__ void k_zero_i(int* p, int n) {
    int i = blockIdx.x * blockDim.x + threadIdx.x;
    if (i < n) p[i] = 0;
}

// 4 edges/thread, int4 dst loads (G13: vectorize streaming reads)
__global__ void k_count(const int* __restrict__ dst, int* cnt, int e) {
    int i = (blockIdx.x * blockDim.x + threadIdx.x) * 4;
    if (i + 3 < e) {
        int4 d4 = *(const int4*)&dst[i];
        atomicAdd(&cnt[d4.x], 1);
        atomicAdd(&cnt[d4.y], 1);
        atomicAdd(&cnt[d4.z], 1);
        atomicAdd(&cnt[d4.w], 1);
    } else {
        for (int k = i; k < e; k++) atomicAdd(&cnt[dst[k]], 1);
    }
}

// block-local exclusive scan: 256 threads x 4 elems = 1024/block
__global__ __launch_bounds__(256) void k_scan1(const int* __restrict__ cnt,
                                               int* __restrict__ offs,
                                               int* __restrict__ bsums, int n)
{
    __shared__ int sm[256];
    int t = threadIdx.x;
    int base = blockIdx.x * 1024 + t * 4;
    int a0 = (base + 0 < n) ? cnt[base + 0] : 0;
    int a1 = (base + 1 < n) ? cnt[base + 1] : 0;
    int a2 = (base + 2 < n) ? cnt[base + 2] : 0;
    int a3 = (base + 3 < n) ? cnt[base + 3] : 0;
    int s = a0 + a1 + a2 + a3;
    sm[t] = s;
    __syncthreads();
#pragma unroll
    for (int off = 1; off < 256; off <<= 1) {
        int v = (t >= off) ? sm[t - off] : 0;
        __syncthreads();
        sm[t] += v;
        __syncthreads();
    }
    int excl = sm[t] - s;
    if (base + 0 < n) offs[base + 0] = excl;
    if (base + 1 < n) offs[base + 1] = excl + a0;
    if (base + 2 < n) offs[base + 2] = excl + a0 + a1;
    if (base + 3 < n) offs[base + 3] = excl + a0 + a1 + a2;
    if (t == 255) bsums[blockIdx.x] = sm[255];
}

// single-block exclusive scan of block sums (nb <= 256)
__global__ __launch_bounds__(256) void k_scan2(int* bsums, int nb)
{
    __shared__ int sm[256];
    int t = threadIdx.x;
    int s = (t < nb) ? bsums[t] : 0;
    sm[t] = s;
    __syncthreads();
#pragma unroll
    for (int off = 1; off < 256; off <<= 1) {
        int v = (t >= off) ? sm[t - off] : 0;
        __syncthreads();
        sm[t] += v;
        __syncthreads();
    }
    if (t < nb) bsums[t] = sm[t] - s;
}

// finalize offsets, init cursor, compute dinv = rsqrt(1 + indeg)
__global__ void k_scan3(int* __restrict__ offs, int* __restrict__ cursor,
                        const int* __restrict__ bsums, const int* __restrict__ cnt,
                        float* __restrict__ dinv, int n)
{
    int i = blockIdx.x * blockDim.x + threadIdx.x;
    if (i >= n) return;
    int o = offs[i] + bsums[i >> 10];
    offs[i] = o;
    cursor[i] = o;
    dinv[i] = rsqrtf((float)(cnt[i] + 1));
}

// windowed fill: csr writes land in ~800 KB contiguous region (L2-resident)
// 4 edges/thread, int4 dst loads; src loaded only when in-window
__global__ void k_fill_win(const int* __restrict__ src, const int* __restrict__ dst,
                           int* cursor, int* __restrict__ csr, int e, int wlo, int whi)
{
    int i = (blockIdx.x * blockDim.x + threadIdx.x) * 4;
    if (i >= e) return;
    if (i + 3 < e) {
        int4 d4 = *(const int4*)&dst[i];
        int dd[4] = {d4.x, d4.y, d4.z, d4.w};
#pragma unroll
        for (int k = 0; k < 4; k++) {
            int d = dd[k];
            if (d >= wlo && d < whi) {
                int p = atomicAdd(&cursor[d], 1);
                csr[p] = src[i + k];
            }
        }
    } else {
        for (int k = i; k < e; k++) {
            int d = dst[k];
            if (d >= wlo && d < whi) {
                int p = atomicAdd(&cursor[d], 1);
                csr[p] = src[k];
            }
        }
    }
}

// ---------------- W1 -> MFMA B-fragment layout, split bf16 hi/lo ----------------
// frag index: idx = ((kstep*2 + ntile)*64 + lane)*8 + j
//   k = kstep*32 + (lane>>4)*8 + j ; ncol = ntile*16 + (lane&15)
__global__ void k_convw(const float* __restrict__ W, unsigned short* __restrict__ wfh,
                        unsigned short* __restrict__ wfl)
{
    int idx = blockIdx.x * blockDim.x + threadIdx.x;  // 16*2*64*8 = 16384
    int j     = idx & 7;
    int lane  = (idx >> 3) & 63;
    int ntile = (idx >> 9) & 1;
    int kstep = idx >> 10;
    int k    = kstep * 32 + (lane >> 4) * 8 + j;
    int ncol = ntile * 16 + (lane & 15);
    float v = W[k * HID + ncol];
    unsigned u = __builtin_bit_cast(unsigned, v);
    unsigned short h = (unsigned short)(u >> 16);  // truncate -> hi
    float hv = __builtin_bit_cast(float, u & 0xFFFF0000u);
    float rem = v - hv;
    unsigned ur = __builtin_bit_cast(unsigned, rem);
    ur += 0x7FFF + ((ur >> 16) & 1);               // RNE -> lo
    wfh[idx] = h;
    wfl[idx] = (unsigned short)(ur >> 16);
}

// ---------------- gemm1 (MFMA split-bf16): g1 = dinv * (x @ W1) ----------------
// 4 waves/block, wave = 16 rows x 32 cols. No LDS, no barriers, no s_loads in loop.
__global__ __launch_bounds__(256) void k_gemm1(
    const float* __restrict__ x,
    const unsigned short* __restrict__ wfh, const unsigned short* __restrict__ wfl,
    const float* __restrict__ dinv, float* __restrict__ g1, int n)
{
    const int t    = threadIdx.x;
    const int lane = t & 63;
    const int wave = t >> 6;
    const int m    = lane & 15;
    const int quad = lane >> 4;
    const int row0 = blockIdx.x * 64 + wave * 16;

    int arow = row0 + m;
    if (arow >= n) arow = n - 1;  // clamp: A row m only feeds output row m (unstored)
    const float* xp = x + (size_t)arow * N_IN + quad * 8;

    f32x4 acc0 = {0.f, 0.f, 0.f, 0.f};
    f32x4 acc1 = {0.f, 0.f, 0.f, 0.f};

    for (int ks = 0; ks < 16; ks++) {
        float4 xa = *(const float4*)(xp + ks * 32);
        float4 xb = *(const float4*)(xp + ks * 32 + 4);
        float xe[8] = {xa.x, xa.y, xa.z, xa.w, xb.x, xb.y, xb.z, xb.w};
        bf16x8 ah, al;
#pragma unroll
        for (int j = 0; j < 8; j++) {
            unsigned u = __builtin_bit_cast(unsigned, xe[j]);
            ah[j] = (short)(u >> 16);                           // truncate -> hi
            float hv = __builtin_bit_cast(float, u & 0xFFFF0000u);
            float rem = xe[j] - hv;
            unsigned ur = __builtin_bit_cast(unsigned, rem);
            ur += 0x7FFF + ((ur >> 16) & 1);                    // RNE -> lo
            al[j] = (short)(ur >> 16);
        }
        bf16x8 bh0 = *(const bf16x8*)(wfh + ((size_t)(ks * 2 + 0) * 64 + lane) * 8);
        bf16x8 bh1 = *(const bf16x8*)(wfh + ((size_t)(ks * 2 + 1) * 64 + lane) * 8);
        bf16x8 bl0 = *(const bf16x8*)(wfl + ((size_t)(ks * 2 + 0) * 64 + lane) * 8);
        bf16x8 bl1 = *(const bf16x8*)(wfl + ((size_t)(ks * 2 + 1) * 64 + lane) * 8);

        acc0 = __builtin_amdgcn_mfma_f32_16x16x32_bf16(ah, bh0, acc0, 0, 0, 0);
        acc0 = __builtin_amdgcn_mfma_f32_16x16x32_bf16(al, bh0, acc0, 0, 0, 0);
        acc0 = __builtin_amdgcn_mfma_f32_16x16x32_bf16(ah, bl0, acc0, 0, 0, 0);
        acc1 = __builtin_amdgcn_mfma_f32_16x16x32_bf16(ah, bh1, acc1, 0, 0, 0);
        acc1 = __builtin_amdgcn_mfma_f32_16x16x32_bf16(al, bh1, acc1, 0, 0, 0);
        acc1 = __builtin_amdgcn_mfma_f32_16x16x32_bf16(ah, bl1, acc1, 0, 0, 0);
    }

    // C/D: col = lane&15 (+16 for ntile1), row = quad*4 + r  [m89-verified mapping]
#pragma unroll
    for (int r = 0; r < 4; r++) {
        int row = row0 + quad * 4 + r;
        if (row < n) {
            float dv = dinv[row];
            g1[(size_t)row * HID + m]      = acc0[r] * dv;
            g1[(size_t)row * HID + 16 + m] = acc1[r] * dv;
        }
    }
}

// ---------------- cooperative gather-aggregate: 16 lanes per node ----------------
// Full 16-edge blocks are compile-time unrolled so the compiler issues
// independent global_load_dwordx4s with counted vmcnt (MLP), instead of
// one-outstanding-load-per-iteration at vmcnt(0).

__global__ void k_agg32(const int* __restrict__ csr, const int* __restrict__ offs,
                        const int* __restrict__ cnt, const float* __restrict__ g,
                        float* __restrict__ acc1, int n)
{
    int gid = blockIdx.x * blockDim.x + threadIdx.x;
    int r  = gid >> 4;
    int sl = gid & 15;
    if (r >= n) return;
    int s0 = offs[r], d = cnt[r];
    const bool act = sl < 8;
    const float* gc = g + sl * 4;
    float4 acc = make_float4(0.f, 0.f, 0.f, 0.f);
    if (act) acc = *(const float4*)&gc[(size_t)r * HID];  // self loop
    int j0 = 0;
    for (; j0 + 16 <= d; j0 += 16) {
        int s = csr[s0 + j0 + sl];
#pragma unroll
        for (int jj = 0; jj < 16; jj++) {
            int sj = __shfl(s, jj, 16);
            if (act) {
                float4 v = *(const float4*)&gc[(size_t)sj * HID];
                acc.x += v.x; acc.y += v.y; acc.z += v.z; acc.w += v.w;
            }
        }
    }
    if (j0 < d) {
        int s = 0;
        if (j0 + sl < d) s = csr[s0 + j0 + sl];
        int mlim = d - j0;
        for (int jj = 0; jj < mlim; jj++) {
            int sj = __shfl(s, jj, 16);
            if (act) {
                float4 v = *(const float4*)&gc[(size_t)sj * HID];
                acc.x += v.x; acc.y += v.y; acc.z += v.z; acc.w += v.w;
            }
        }
    }
    if (act) *(float4*)&acc1[(size_t)r * HID + sl * 4] = acc;
}

__global__ void k_agg40(const int* __restrict__ csr, const int* __restrict__ offs,
                        const int* __restrict__ cnt, const float* __restrict__ g,
                        const float* __restrict__ dinv, const float* __restrict__ b2,
                        float* __restrict__ out, int n)
{
    int gid = blockIdx.x * blockDim.x + threadIdx.x;
    int r  = gid >> 4;
    int sl = gid & 15;
    if (r >= n) return;
    int s0 = offs[r], d = cnt[r];
    const bool act = sl < 10;
    const float* gc = g + sl * 4;
    float4 acc = make_float4(0.f, 0.f, 0.f, 0.f);
    if (act) acc = *(const float4*)&gc[(size_t)r * OUTD];  // self loop
    int j0 = 0;
    for (; j0 + 16 <= d; j0 += 16) {
        int s = csr[s0 + j0 + sl];
#pragma unroll
        for (int jj = 0; jj < 16; jj++) {
            int sj = __shfl(s, jj, 16);
            if (act) {
                float4 v = *(const float4*)&gc[(size_t)sj * OUTD];
                acc.x += v.x; acc.y += v.y; acc.z += v.z; acc.w += v.w;
            }
        }
    }
    if (j0 < d) {
        int s = 0;
        if (j0 + sl < d) s = csr[s0 + j0 + sl];
        int mlim = d - j0;
        for (int jj = 0; jj < mlim; jj++) {
            int sj = __shfl(s, jj, 16);
            if (act) {
                float4 v = *(const float4*)&gc[(size_t)sj * OUTD];
                acc.x += v.x; acc.y += v.y; acc.z += v.z; acc.w += v.w;
            }
        }
    }
    if (act) {
        float dv = dinv[r];
        float4 bv = *(const float4*)&b2[sl * 4];
        float4 o;
        o.x = acc.x * dv + bv.x;
        o.y = acc.y * dv + bv.y;
        o.z = acc.z * dv + bv.z;
        o.w = acc.w * dv + bv.w;
        *(float4*)&out[(size_t)r * OUTD + sl * 4] = o;
    }
}

// ---------------- gemm2: g2 = dinv * (relu(dinv*acc1 + b1) @ W2) ----------------
__global__ void k_gemm2(const float* __restrict__ acc1, const float* __restrict__ b1,
                        const float* __restrict__ W2, const float* __restrict__ dinv,
                        float* __restrict__ g2, int n)
{
    int r = blockIdx.x * blockDim.x + threadIdx.x;
    if (r >= n) return;
    float dv = dinv[r];
    float h[HID];
#pragma unroll
    for (int k4 = 0; k4 < HID / 4; k4++) {
        float4 v  = *(const float4*)&acc1[(size_t)r * HID + k4 * 4];
        float4 bv = *(const float4*)&b1[k4 * 4];
        h[k4 * 4 + 0] = fmaxf(v.x * dv + bv.x, 0.f);
        h[k4 * 4 + 1] = fmaxf(v.y * dv + bv.y, 0.f);
        h[k4 * 4 + 2] = fmaxf(v.z * dv + bv.z, 0.f);
        h[k4 * 4 + 3] = fmaxf(v.w * dv + bv.w, 0.f);
    }
    float o[OUTD];
#pragma unroll
    for (int c = 0; c < OUTD; c++) o[c] = 0.f;
#pragma unroll
    for (int k = 0; k < HID; k++) {
        float hv = h[k];
        const float* wr = &W2[k * OUTD];  // uniform -> s_load
#pragma unroll
        for (int c = 0; c < OUTD; c++) o[c] += hv * wr[c];
    }
    float* gp = &g2[(size_t)r * OUTD];
#pragma unroll
    for (int c4 = 0; c4 < OUTD / 4; c4++) {
        float4 v;
        v.x = o[c4 * 4 + 0] * dv;
        v.y = o[c4 * 4 + 1] * dv;
        v.z = o[c4 * 4 + 2] * dv;
        v.w = o[c4 * 4 + 3] * dv;
        *(float4*)&gp[c4 * 4] = v;
    }
}

extern "C" void kernel_launch(void* const* d_in, const int* in_sizes, int n_in,
                              void* d_out, int out_size, void* d_ws, size_t ws_size,
                              hipStream_t stream)
{
    const float* x  = (const float*)d_in[0];
    const int*   ei = (const int*)d_in[1];
    const float* W1 = (const float*)d_in[2];
    const float* b1 = (const float*)d_in[3];
    const float* W2 = (const float*)d_in[4];
    const float* b2 = (const float*)d_in[5];
    float* out = (float*)d_out;

    const int n = in_sizes[0] / N_IN;  // 100000
    const int e = in_sizes[1] / 2;     // 1600000
    const int* src = ei;
    const int* dst = ei + e;

    char* w = (char*)d_ws;
    float* dinv   = (float*)w;            w += sizeof(float) * (size_t)((n + 3) & ~3);
    float* g1     = (float*)w;            w += sizeof(float) * (size_t)n * HID;
    float* acc1   = (float*)w;            w += sizeof(float) * (size_t)n * HID;
    float* g2     = (float*)w;            w += sizeof(float) * (size_t)n * OUTD;
    int*   cnt    = (int*)w;              w += sizeof(int) * (size_t)((n + 3) & ~3);
    int*   offs   = (int*)w;              w += sizeof(int) * (size_t)((n + 3) & ~3);
    int*   cursor = (int*)w;              w += sizeof(int) * (size_t)((n + 3) & ~3);
    int*   bsums  = (int*)w;              w += sizeof(int) * 1024;
    unsigned short* wfh = (unsigned short*)w;  w += sizeof(unsigned short) * 16384;
    unsigned short* wfl = (unsigned short*)w;  w += sizeof(unsigned short) * 16384;
    int*   csr    = (int*)w;              w += sizeof(int) * (size_t)e;

    const int nb = (n + 1023) / 1024;
    const int ec = (e + 3) / 4;  // 4 edges/thread for count & fill

    k_zero_i<<<(n + 255) / 256, 256, 0, stream>>>(cnt, n);
    k_count<<<(ec + 255) / 256, 256, 0, stream>>>(dst, cnt, e);
    k_scan1<<<nb, 256, 0, stream>>>(cnt, offs, bsums, n);
    k_scan2<<<1, 256, 0, stream>>>(bsums, nb);
    k_scan3<<<(n + 255) / 256, 256, 0, stream>>>(offs, cursor, bsums, cnt, dinv, n);

    for (int wdx = 0; wdx < NWIN; wdx++) {
        int wlo = (int)((long)n * wdx / NWIN);
        int whi = (int)((long)n * (wdx + 1) / NWIN);
        k_fill_win<<<(ec + 255) / 256, 256, 0, stream>>>(src, dst, cursor, csr, e, wlo, whi);
    }

    k_convw<<<64, 256, 0, stream>>>(W1, wfh, wfl);

    k_gemm1<<<(n + 63) / 64, 256, 0, stream>>>(x, wfh, wfl, dinv, g1, n);

    int t32 = n * 16;
    k_agg32<<<(t32 + 255) / 256, 256, 0, stream>>>(csr, offs, cnt, g1, acc1, n);

    k_gemm2<<<(n + 255) / 256, 256, 0, stream>>>(acc1, b1, W2, dinv, g2, n);

    int t40 = n * 16;
    k_agg40<<<(t40 + 255) / 256, 256, 0, stream>>>(csr, offs, cnt, g2, dinv, b2, out, n);
}

// Round 4
// 578.398 us; speedup vs baseline: 1.0822x; 1.0822x over previous
//
#include <hip/hip_runtime.h>
#include <hip/hip_bf16.h>

#define N_IN 512
#define HID 32
#define OUTD 40
#define NWIN 8  // fill windows: csr region per window ~1.2 MB -> L2-resident writes

typedef __attribute__((ext_vector_type(8))) short bf16x8;
typedef __attribute__((ext_vector_type(4))) float f32x4;

// ---------------- degree / CSR build ----------------

__global__ void k_zero_i(int* p, int n) {
    int i = blockIdx.x * blockDim.x + threadIdx.x;
    if (i < n) p[i] = 0;
}

// 4 edges/thread, int4 dst loads (G13: vectorize streaming reads)
__global__ void k_count(const int* __restrict__ dst, int* cnt, int e) {
    int i = (blockIdx.x * blockDim.x + threadIdx.x) * 4;
    if (i + 3 < e) {
        int4 d4 = *(const int4*)&dst[i];
        atomicAdd(&cnt[d4.x], 1);
        atomicAdd(&cnt[d4.y], 1);
        atomicAdd(&cnt[d4.z], 1);
        atomicAdd(&cnt[d4.w], 1);
    } else {
        for (int k = i; k < e; k++) atomicAdd(&cnt[dst[k]], 1);
    }
}

// pre-init csr to sentinel n (zero-row index); also zero the pad rows of g1 and p
__global__ void k_fill_pad(int* __restrict__ csr, int tot4, int n,
                           float* __restrict__ g1, float* __restrict__ p)
{
    int i = blockIdx.x * blockDim.x + threadIdx.x;
    if (i < tot4) {
        int4 v = make_int4(n, n, n, n);
        *(int4*)&csr[(size_t)i * 4] = v;
    }
    if (blockIdx.x == 0) {
        float4 z = make_float4(0.f, 0.f, 0.f, 0.f);
        if (threadIdx.x < 8)
            *(float4*)&g1[(size_t)n * HID + threadIdx.x * 4] = z;
        else if (threadIdx.x < 16)
            *(float4*)&p[(size_t)n * HID + (threadIdx.x - 8) * 4] = z;
    }
}

// block-local exclusive scan over PADDED degrees: 256 threads x 4 elems
__global__ __launch_bounds__(256) void k_scan1(const int* __restrict__ cnt,
                                               int* __restrict__ offs,
                                               int* __restrict__ bsums, int n)
{
    __shared__ int sm[256];
    int t = threadIdx.x;
    int base = blockIdx.x * 1024 + t * 4;
    int a0 = (base + 0 < n) ? cnt[base + 0] : 0;
    int a1 = (base + 1 < n) ? cnt[base + 1] : 0;
    int a2 = (base + 2 < n) ? cnt[base + 2] : 0;
    int a3 = (base + 3 < n) ? cnt[base + 3] : 0;
    int d0 = (a0 + 15) & ~15;
    int d1 = (a1 + 15) & ~15;
    int d2 = (a2 + 15) & ~15;
    int d3 = (a3 + 15) & ~15;
    int s = d0 + d1 + d2 + d3;
    sm[t] = s;
    __syncthreads();
#pragma unroll
    for (int off = 1; off < 256; off <<= 1) {
        int v = (t >= off) ? sm[t - off] : 0;
        __syncthreads();
        sm[t] += v;
        __syncthreads();
    }
    int excl = sm[t] - s;
    if (base + 0 < n) offs[base + 0] = excl;
    if (base + 1 < n) offs[base + 1] = excl + d0;
    if (base + 2 < n) offs[base + 2] = excl + d0 + d1;
    if (base + 3 < n) offs[base + 3] = excl + d0 + d1 + d2;
    if (t == 255) bsums[blockIdx.x] = sm[255];
}

// single-block exclusive scan of block sums (nb <= 256)
__global__ __launch_bounds__(256) void k_scan2(int* bsums, int nb)
{
    __shared__ int sm[256];
    int t = threadIdx.x;
    int s = (t < nb) ? bsums[t] : 0;
    sm[t] = s;
    __syncthreads();
#pragma unroll
    for (int off = 1; off < 256; off <<= 1) {
        int v = (t >= off) ? sm[t - off] : 0;
        __syncthreads();
        sm[t] += v;
        __syncthreads();
    }
    if (t < nb) bsums[t] = sm[t] - s;
}

// finalize offsets, init cursor, compute dinv = rsqrt(1 + indeg)
__global__ void k_scan3(int* __restrict__ offs, int* __restrict__ cursor,
                        const int* __restrict__ bsums, const int* __restrict__ cnt,
                        float* __restrict__ dinv, int n)
{
    int i = blockIdx.x * blockDim.x + threadIdx.x;
    if (i >= n) return;
    int o = offs[i] + bsums[i >> 10];
    offs[i] = o;
    cursor[i] = o;
    dinv[i] = rsqrtf((float)(cnt[i] + 1));
}

// windowed fill: csr writes land in a contiguous region (L2-resident)
__global__ void k_fill_win(const int* __restrict__ src, const int* __restrict__ dst,
                           int* cursor, int* __restrict__ csr, int e, int wlo, int whi)
{
    int i = (blockIdx.x * blockDim.x + threadIdx.x) * 4;
    if (i >= e) return;
    if (i + 3 < e) {
        int4 d4 = *(const int4*)&dst[i];
        int dd[4] = {d4.x, d4.y, d4.z, d4.w};
#pragma unroll
        for (int k = 0; k < 4; k++) {
            int d = dd[k];
            if (d >= wlo && d < whi) {
                int p = atomicAdd(&cursor[d], 1);
                csr[p] = src[i + k];
            }
        }
    } else {
        for (int k = i; k < e; k++) {
            int d = dst[k];
            if (d >= wlo && d < whi) {
                int p = atomicAdd(&cursor[d], 1);
                csr[p] = src[k];
            }
        }
    }
}

// ---------------- W1 -> MFMA B-fragment layout, split bf16 hi/lo ----------------
__global__ void k_convw(const float* __restrict__ W, unsigned short* __restrict__ wfh,
                        unsigned short* __restrict__ wfl)
{
    int idx = blockIdx.x * blockDim.x + threadIdx.x;  // 16*2*64*8 = 16384
    int j     = idx & 7;
    int lane  = (idx >> 3) & 63;
    int ntile = (idx >> 9) & 1;
    int kstep = idx >> 10;
    int k    = kstep * 32 + (lane >> 4) * 8 + j;
    int ncol = ntile * 16 + (lane & 15);
    float v = W[k * HID + ncol];
    unsigned u = __builtin_bit_cast(unsigned, v);
    unsigned short h = (unsigned short)(u >> 16);  // truncate -> hi
    float hv = __builtin_bit_cast(float, u & 0xFFFF0000u);
    float rem = v - hv;
    unsigned ur = __builtin_bit_cast(unsigned, rem);
    ur += 0x7FFF + ((ur >> 16) & 1);               // RNE -> lo
    wfh[idx] = h;
    wfl[idx] = (unsigned short)(ur >> 16);
}

// ---------------- gemm1 (MFMA split-bf16): g1 = dinv * (x @ W1) ----------------
__global__ __launch_bounds__(256) void k_gemm1(
    const float* __restrict__ x,
    const unsigned short* __restrict__ wfh, const unsigned short* __restrict__ wfl,
    const float* __restrict__ dinv, float* __restrict__ g1, int n)
{
    const int t    = threadIdx.x;
    const int lane = t & 63;
    const int wave = t >> 6;
    const int m    = lane & 15;
    const int quad = lane >> 4;
    const int row0 = blockIdx.x * 64 + wave * 16;

    int arow = row0 + m;
    if (arow >= n) arow = n - 1;  // clamp: A row m only feeds output row m (unstored)
    const float* xp = x + (size_t)arow * N_IN + quad * 8;

    f32x4 acc0 = {0.f, 0.f, 0.f, 0.f};
    f32x4 acc1 = {0.f, 0.f, 0.f, 0.f};

    for (int ks = 0; ks < 16; ks++) {
        float4 xa = *(const float4*)(xp + ks * 32);
        float4 xb = *(const float4*)(xp + ks * 32 + 4);
        float xe[8] = {xa.x, xa.y, xa.z, xa.w, xb.x, xb.y, xb.z, xb.w};
        bf16x8 ah, al;
#pragma unroll
        for (int j = 0; j < 8; j++) {
            unsigned u = __builtin_bit_cast(unsigned, xe[j]);
            ah[j] = (short)(u >> 16);                           // truncate -> hi
            float hv = __builtin_bit_cast(float, u & 0xFFFF0000u);
            float rem = xe[j] - hv;
            unsigned ur = __builtin_bit_cast(unsigned, rem);
            ur += 0x7FFF + ((ur >> 16) & 1);                    // RNE -> lo
            al[j] = (short)(ur >> 16);
        }
        bf16x8 bh0 = *(const bf16x8*)(wfh + ((size_t)(ks * 2 + 0) * 64 + lane) * 8);
        bf16x8 bh1 = *(const bf16x8*)(wfh + ((size_t)(ks * 2 + 1) * 64 + lane) * 8);
        bf16x8 bl0 = *(const bf16x8*)(wfl + ((size_t)(ks * 2 + 0) * 64 + lane) * 8);
        bf16x8 bl1 = *(const bf16x8*)(wfl + ((size_t)(ks * 2 + 1) * 64 + lane) * 8);

        acc0 = __builtin_amdgcn_mfma_f32_16x16x32_bf16(ah, bh0, acc0, 0, 0, 0);
        acc0 = __builtin_amdgcn_mfma_f32_16x16x32_bf16(al, bh0, acc0, 0, 0, 0);
        acc0 = __builtin_amdgcn_mfma_f32_16x16x32_bf16(ah, bl0, acc0, 0, 0, 0);
        acc1 = __builtin_amdgcn_mfma_f32_16x16x32_bf16(ah, bh1, acc1, 0, 0, 0);
        acc1 = __builtin_amdgcn_mfma_f32_16x16x32_bf16(al, bh1, acc1, 0, 0, 0);
        acc1 = __builtin_amdgcn_mfma_f32_16x16x32_bf16(ah, bl1, acc1, 0, 0, 0);
    }

    // C/D: col = lane&15 (+16 for ntile1), row = quad*4 + r  [m89-verified mapping]
#pragma unroll
    for (int r = 0; r < 4; r++) {
        int row = row0 + quad * 4 + r;
        if (row < n) {
            float dv = dinv[row];
            g1[(size_t)row * HID + m]      = acc0[r] * dv;
            g1[(size_t)row * HID + 16 + m] = acc1[r] * dv;
        }
    }
}

// ---------------- padded paired gather-aggregate: 16 lanes per node ----------------
// Degrees padded to x16 with sentinel index n (zero row): branch-free, fully
// unrolled gather loop. Lanes 0-7 process edges j..j+7, lanes 8-15 edges j+8..j+15
// of the same 16-block (all 16 lanes issue loads, 8-deep MLP per lane).

// layer-1 epilogue: p[r] = dinv[r] * relu(dinv[r]*acc + b1)
__global__ void k_agg1(const int* __restrict__ csr, const int* __restrict__ offs,
                       const int* __restrict__ cnt, const float* __restrict__ g,
                       const float* __restrict__ dinv, const float* __restrict__ b1,
                       float* __restrict__ p, int n)
{
    int gid = blockIdx.x * blockDim.x + threadIdx.x;
    int r  = gid >> 4;
    int sl = gid & 15;
    if (r >= n) return;
    int s0 = offs[r];
    int dp = (cnt[r] + 15) & ~15;
    int half = sl >> 3;
    int c = sl & 7;
    const float* gc = g + c * 4;
    float4 acc = make_float4(0.f, 0.f, 0.f, 0.f);
    if (half == 0) acc = *(const float4*)&gc[(size_t)r * HID];  // self loop
    for (int b = 0; b < dp; b += 16) {
        int s = csr[s0 + b + sl];
#pragma unroll
        for (int jj = 0; jj < 8; jj++) {
            int sj = __shfl(s, jj + (half << 3), 16);
            float4 v = *(const float4*)&gc[(size_t)sj * HID];
            acc.x += v.x; acc.y += v.y; acc.z += v.z; acc.w += v.w;
        }
    }
    float4 o;
    o.x = __shfl(acc.x, sl ^ 8, 16);
    o.y = __shfl(acc.y, sl ^ 8, 16);
    o.z = __shfl(acc.z, sl ^ 8, 16);
    o.w = __shfl(acc.w, sl ^ 8, 16);
    if (half == 0) {
        float dv = dinv[r];
        float4 bv = *(const float4*)&b1[c * 4];
        float4 hp;
        hp.x = dv * fmaxf((acc.x + o.x) * dv + bv.x, 0.f);
        hp.y = dv * fmaxf((acc.y + o.y) * dv + bv.y, 0.f);
        hp.z = dv * fmaxf((acc.z + o.z) * dv + bv.z, 0.f);
        hp.w = dv * fmaxf((acc.w + o.w) * dv + bv.w, 0.f);
        *(float4*)&p[(size_t)r * HID + c * 4] = hp;
    }
}

// layer-2 aggregation: acc2[r] = dinv[r] * sum_{s in N^(r)} p[s]
__global__ void k_agg2(const int* __restrict__ csr, const int* __restrict__ offs,
                       const int* __restrict__ cnt, const float* __restrict__ g,
                       const float* __restrict__ dinv, float* __restrict__ acc2, int n)
{
    int gid = blockIdx.x * blockDim.x + threadIdx.x;
    int r  = gid >> 4;
    int sl = gid & 15;
    if (r >= n) return;
    int s0 = offs[r];
    int dp = (cnt[r] + 15) & ~15;
    int half = sl >> 3;
    int c = sl & 7;
    const float* gc = g + c * 4;
    float4 acc = make_float4(0.f, 0.f, 0.f, 0.f);
    if (half == 0) acc = *(const float4*)&gc[(size_t)r * HID];  // self loop
    for (int b = 0; b < dp; b += 16) {
        int s = csr[s0 + b + sl];
#pragma unroll
        for (int jj = 0; jj < 8; jj++) {
            int sj = __shfl(s, jj + (half << 3), 16);
            float4 v = *(const float4*)&gc[(size_t)sj * HID];
            acc.x += v.x; acc.y += v.y; acc.z += v.z; acc.w += v.w;
        }
    }
    float4 o;
    o.x = __shfl(acc.x, sl ^ 8, 16);
    o.y = __shfl(acc.y, sl ^ 8, 16);
    o.z = __shfl(acc.z, sl ^ 8, 16);
    o.w = __shfl(acc.w, sl ^ 8, 16);
    if (half == 0) {
        float dv = dinv[r];
        float4 v;
        v.x = (acc.x + o.x) * dv;
        v.y = (acc.y + o.y) * dv;
        v.z = (acc.z + o.z) * dv;
        v.w = (acc.w + o.w) * dv;
        *(float4*)&acc2[(size_t)r * HID + c * 4] = v;
    }
}

// ---------------- out = acc2 @ W2 + b2 (per-node, uniform W2 -> s_loads) ----------
__global__ void k_out(const float* __restrict__ acc2, const float* __restrict__ W2,
                      const float* __restrict__ b2, float* __restrict__ out, int n)
{
    int r = blockIdx.x * blockDim.x + threadIdx.x;
    if (r >= n) return;
    float h[HID];
#pragma unroll
    for (int k4 = 0; k4 < HID / 4; k4++) {
        float4 v = *(const float4*)&acc2[(size_t)r * HID + k4 * 4];
        h[k4 * 4 + 0] = v.x;
        h[k4 * 4 + 1] = v.y;
        h[k4 * 4 + 2] = v.z;
        h[k4 * 4 + 3] = v.w;
    }
    float o[OUTD];
#pragma unroll
    for (int c = 0; c < OUTD; c++) o[c] = b2[c];
#pragma unroll
    for (int k = 0; k < HID; k++) {
        float hv = h[k];
        const float* wr = &W2[k * OUTD];  // uniform -> s_load
#pragma unroll
        for (int c = 0; c < OUTD; c++) o[c] += hv * wr[c];
    }
    float* gp = &out[(size_t)r * OUTD];
#pragma unroll
    for (int c4 = 0; c4 < OUTD / 4; c4++) {
        float4 v;
        v.x = o[c4 * 4 + 0];
        v.y = o[c4 * 4 + 1];
        v.z = o[c4 * 4 + 2];
        v.w = o[c4 * 4 + 3];
        *(float4*)&gp[c4 * 4] = v;
    }
}

extern "C" void kernel_launch(void* const* d_in, const int* in_sizes, int n_in,
                              void* d_out, int out_size, void* d_ws, size_t ws_size,
                              hipStream_t stream)
{
    const float* x  = (const float*)d_in[0];
    const int*   ei = (const int*)d_in[1];
    const float* W1 = (const float*)d_in[2];
    const float* b1 = (const float*)d_in[3];
    const float* W2 = (const float*)d_in[4];
    const float* b2 = (const float*)d_in[5];
    float* out = (float*)d_out;

    const int n = in_sizes[0] / N_IN;  // 100000
    const int e = in_sizes[1] / 2;     // 1600000
    const int* src = ei;
    const int* dst = ei + e;

    const int csr_cap = e + 16 * n;  // padded capacity

    char* w = (char*)d_ws;
    float* dinv   = (float*)w;            w += sizeof(float) * (size_t)((n + 3) & ~3);
    float* g1     = (float*)w;            w += sizeof(float) * (size_t)(n + 1) * HID;
    float* p      = (float*)w;            w += sizeof(float) * (size_t)(n + 1) * HID;
    float* acc2   = (float*)w;            w += sizeof(float) * (size_t)n * HID;
    int*   cnt    = (int*)w;              w += sizeof(int) * (size_t)((n + 3) & ~3);
    int*   offs   = (int*)w;              w += sizeof(int) * (size_t)((n + 3) & ~3);
    int*   cursor = (int*)w;              w += sizeof(int) * (size_t)((n + 3) & ~3);
    int*   bsums  = (int*)w;              w += sizeof(int) * 1024;
    unsigned short* wfh = (unsigned short*)w;  w += sizeof(unsigned short) * 16384;
    unsigned short* wfl = (unsigned short*)w;  w += sizeof(unsigned short) * 16384;
    int*   csr    = (int*)w;              w += sizeof(int) * (size_t)((csr_cap + 3) & ~3);

    const int nb = (n + 1023) / 1024;
    const int ec = (e + 3) / 4;            // 4 edges/thread for count & fill
    const int tot4 = (csr_cap + 3) / 4;    // int4 units for csr pre-init

    k_zero_i<<<(n + 255) / 256, 256, 0, stream>>>(cnt, n);
    k_count<<<(ec + 255) / 256, 256, 0, stream>>>(dst, cnt, e);
    k_fill_pad<<<(tot4 + 255) / 256, 256, 0, stream>>>(csr, tot4, n, g1, p);
    k_scan1<<<nb, 256, 0, stream>>>(cnt, offs, bsums, n);
    k_scan2<<<1, 256, 0, stream>>>(bsums, nb);
    k_scan3<<<(n + 255) / 256, 256, 0, stream>>>(offs, cursor, bsums, cnt, dinv, n);

    for (int wdx = 0; wdx < NWIN; wdx++) {
        int wlo = (int)((long)n * wdx / NWIN);
        int whi = (int)((long)n * (wdx + 1) / NWIN);
        k_fill_win<<<(ec + 255) / 256, 256, 0, stream>>>(src, dst, cursor, csr, e, wlo, whi);
    }

    k_convw<<<64, 256, 0, stream>>>(W1, wfh, wfl);

    k_gemm1<<<(n + 63) / 64, 256, 0, stream>>>(x, wfh, wfl, dinv, g1, n);

    int t16 = n * 16;
    k_agg1<<<(t16 + 255) / 256, 256, 0, stream>>>(csr, offs, cnt, g1, dinv, b1, p, n);
    k_agg2<<<(t16 + 255) / 256, 256, 0, stream>>>(csr, offs, cnt, p, dinv, acc2, n);

    k_out<<<(n + 255) / 256, 256, 0, stream>>>(acc2, W2, b2, out, n);
}